// Round 1
// baseline (84.794 us; speedup 1.0000x reference)
//
#include <hip/hip_runtime.h>
#include <hip/hip_bf16.h>
#include <math.h>

// Problem constants (match reference)
#define BQ     8
#define TDEC   256
#define VV     16000        // V
#define TJ     256          // T1 == T2
#define NOOV   256          // VOOV - V
#define NEGV   (-1e20f)
#define NTHREADS 1024

// One block per (b,t) row.
// Dense c1/c2 scatter arrays (the nonzero part of cps1/cps2 in [0,V)) live in LDS.
// gen row lives in registers (read from HBM once).
__global__ __launch_bounds__(NTHREADS) void pointer_softmax_kernel(
    const float* __restrict__ gen,
    const float* __restrict__ cp1,
    const float* __restrict__ cp2,
    const int*   __restrict__ idx1,
    const int*   __restrict__ idx2,
    float* __restrict__ out)
{
    __shared__ float c1[VV];
    __shared__ float c2[VV];
    __shared__ float oovacc[NOOV];
    __shared__ float red[NTHREADS / 64];

    const int row = blockIdx.x;       // b*TDEC + t
    const int b   = row >> 8;         // TDEC == 256
    const int tid = threadIdx.x;

    // ---- zero LDS ----
    for (int i = tid; i < VV; i += NTHREADS) { c1[i] = 0.f; c2[i] = 0.f; }
    if (tid < NOOV) oovacc[tid] = 0.f;

    // ---- load gen row into registers (coalesced, stride-1024) ----
    const float* grow = gen + (size_t)row * VV;
    float g[16];
#pragma unroll
    for (int k = 0; k < 16; ++k) {
        int n = k * NTHREADS + tid;
        g[k] = (n < VV) ? grow[n] : NEGV;   // NEGV only used for max; sum/out guarded by n<VV
    }

    // ---- load cp rows + indices (one entry per thread tid<256) ----
    float mycp1 = 0.f, mycp2 = 0.f;
    int   myi1 = -1,   myi2 = -1;
    if (tid < TJ) {
        mycp1 = cp1[(size_t)row * TJ + tid];
        mycp2 = cp2[(size_t)row * TJ + tid];
        myi1  = idx1[b * TJ + tid];
        myi2  = idx2[b * TJ + tid];
    }
    __syncthreads();   // LDS zeroing complete

    // ---- dense scatter (collisions handled by LDS atomics; idx==0 dropped) ----
    if (tid < TJ) {
        if (myi1 > 0 && myi1 < VV) atomicAdd(&c1[myi1], mycp1);
        if (myi2 > 0 && myi2 < VV) atomicAdd(&c2[myi2], mycp2);
    }
    __syncthreads();

    // ---- global max over the 48512-wide concat ----
    // zero columns always exist (c1[0]==0), so m >= 0 via scanning the dense arrays.
    float m = 0.f;
#pragma unroll
    for (int k = 0; k < 16; ++k) m = fmaxf(m, g[k]);
    for (int i = tid; i < VV; i += NTHREADS) m = fmaxf(m, fmaxf(c1[i], c2[i]));
    if (tid < TJ) {
        if (myi1 >= VV) m = fmaxf(m, mycp1);   // cps1 column V+j value
        if (myi2 >= VV) m = fmaxf(m, mycp2);
    }
#pragma unroll
    for (int o = 32; o > 0; o >>= 1) m = fmaxf(m, __shfl_down(m, o, 64));
    if ((tid & 63) == 0) red[tid >> 6] = m;
    __syncthreads();
    if (tid == 0) {
        float mm = red[0];
        for (int w = 1; w < NTHREADS / 64; ++w) mm = fmaxf(mm, red[w]);
        red[0] = mm;
    }
    __syncthreads();
    m = red[0];
    __syncthreads();   // red[] reused below

    // ---- Z = sum(exp(x - m)) over all 48512 columns ----
    // Overwrite g[] and c1/c2 with exp(x-m) so pass 2 needs no re-exp.
    float z = 0.f;
#pragma unroll
    for (int k = 0; k < 16; ++k) {
        int n = k * NTHREADS + tid;
        if (n < VV) { float e = __expf(g[k] - m); g[k] = e; z += e; }
    }
    for (int i = tid; i < VV; i += NTHREADS) {
        float e1 = __expf(c1[i] - m);
        float e2 = __expf(c2[i] - m);
        c1[i] = e1; c2[i] = e2;
        z += e1 + e2;
    }
    if (tid < TJ) {
        // columns V..V+TJ-1 of cps1/cps2: value cp if idx>=V else exactly 0
        z += (myi1 >= VV) ? __expf(mycp1 - m) : __expf(-m);
        z += (myi2 >= VV) ? __expf(mycp2 - m) : __expf(-m);
    }
#pragma unroll
    for (int o = 32; o > 0; o >>= 1) z += __shfl_down(z, o, 64);
    if ((tid & 63) == 0) red[tid >> 6] = z;
    __syncthreads();
    if (tid == 0) {
        float zz = 0.f;
        for (int w = 0; w < NTHREADS / 64; ++w) zz += red[w];
        red[0] = zz;
    }
    __syncthreads();
    z = red[0];
    const float logZ = __logf(z);

    // ---- OOV scatter: LSE over all j with idx==V+p ----
    if (tid < TJ) {
        if (myi1 >= VV) atomicAdd(&oovacc[myi1 - VV], __expf(mycp1 - m));
        if (myi2 >= VV) atomicAdd(&oovacc[myi2 - VV], __expf(mycp2 - m));
    }

    // ---- pass 2: gen region output ----
    float* orow = out + (size_t)row * (VV + NOOV);
#pragma unroll
    for (int k = 0; k < 16; ++k) {
        int n = k * NTHREADS + tid;
        if (n < VV) orow[n] = __logf(g[k] + c1[n] + c2[n]) - logZ;
    }

    __syncthreads();   // oov atomics complete
    if (tid < NOOV) {
        float a = oovacc[tid];
        orow[VV + tid] = (a > 0.f) ? (__logf(a) - logZ) : NEGV;
    }
}

extern "C" void kernel_launch(void* const* d_in, const int* in_sizes, int n_in,
                              void* d_out, int out_size, void* d_ws, size_t ws_size,
                              hipStream_t stream) {
    const float* gen  = (const float*)d_in[0];
    const float* cp1  = (const float*)d_in[1];
    const float* cp2  = (const float*)d_in[2];
    // d_in[3], d_in[4] = onehot1/onehot2 — never read (reconstructed from indices)
    const int*   idx1 = (const int*)d_in[5];
    const int*   idx2 = (const int*)d_in[6];
    float* out = (float*)d_out;

    hipLaunchKernelGGL(pointer_softmax_kernel,
                       dim3(BQ * TDEC), dim3(NTHREADS), 0, stream,
                       gen, cp1, cp2, idx1, idx2, out);
}